// Round 5
// baseline (273.846 us; speedup 1.0000x reference)
//
#include <hip/hip_runtime.h>
#include <math.h>

// Problem constants
constexpr int Bb = 4, Ll = 2048, Ss = 2048, Hh = 16, Ee = 64;
constexpr float S2E  = 0.125f * 1.44269504088896341f;  // SCALE * log2(e)
constexpr float EPS2 = 1e-8f * S2E * S2E;
constexpr float INV_CNT = 1.0f / (4.0f * 16.0f * 2048.0f * 2048.0f);
constexpr float SUM_SCALE = INV_CNT * 0.69314718055994531f;  // scsum is score*log2e

typedef __attribute__((ext_vector_type(8))) short  short8;
typedef __attribute__((ext_vector_type(4))) short  short4v;
typedef __attribute__((ext_vector_type(4))) float  floatx4;

#define MFMA32(A, B, C) __builtin_amdgcn_mfma_f32_16x16x32_bf16(A, B, C, 0, 0, 0)

#if __has_builtin(__builtin_amdgcn_mfma_f32_16x16x16_bf16)
#define MFMA16(A, B, C) __builtin_amdgcn_mfma_f32_16x16x16_bf16(A, B, C, 0, 0, 0)
#elif __has_builtin(__builtin_amdgcn_mfma_f32_16x16x16bf16_1k)
#define MFMA16(A, B, C) __builtin_amdgcn_mfma_f32_16x16x16bf16_1k(A, B, C, 0, 0, 0)
#else
static __device__ __forceinline__ floatx4 mfma16_asm(short4v a, short4v b, floatx4 c) {
  floatx4 d;
  asm volatile("v_mfma_f32_16x16x16_bf16 %0, %1, %2, %3"
               : "=v"(d) : "v"(a), "v"(b), "v"(c));
  return d;
}
#define MFMA16(A, B, C) mfma16_asm(A, B, C)
#endif

// async global(16B/lane) -> LDS (wave-uniform dst base + lane*16)
#define GLL(gp, lp_)                                                       \
  __builtin_amdgcn_global_load_lds(                                        \
      (const __attribute__((address_space(1))) unsigned int*)(gp),         \
      (__attribute__((address_space(3))) unsigned int*)(lp_), 16, 0, 0)

__device__ __forceinline__ unsigned bfrnd(float f) {  // RNE, bf16 in high 16
  unsigned u = __builtin_bit_cast(unsigned, f);
  return u + 0x7fffu + ((u >> 16) & 1u);
}
__device__ __forceinline__ float sq4(float4 v) {
  return v.x * v.x + v.y * v.y + v.z * v.z + v.w * v.w;
}
__device__ __forceinline__ float4 mul4(float4 v, float s) {
  float4 r; r.x = v.x * s; r.y = v.y * s; r.z = v.z * s; r.w = v.w * s;
  return r;
}
__device__ __forceinline__ short8 pack8(float4 x, float4 y) {
  union { short8 s; unsigned u[4]; } r;
  r.u[0] = __builtin_amdgcn_perm(bfrnd(x.y), bfrnd(x.x), 0x07060302u);
  r.u[1] = __builtin_amdgcn_perm(bfrnd(x.w), bfrnd(x.z), 0x07060302u);
  r.u[2] = __builtin_amdgcn_perm(bfrnd(y.y), bfrnd(y.x), 0x07060302u);
  r.u[3] = __builtin_amdgcn_perm(bfrnd(y.w), bfrnd(y.z), 0x07060302u);
  return r.s;
}

// ---- Pre-pass: K->bf16 [bh][s][e]; V->bf16^T [bh][d][s] with per-row granule
//      rotation (pos = (cp*4+q4 + (d&7)) & 7, halves = ct pair); kn2 ----
__global__ __launch_bounds__(256) void geom_pre_kernel(
    const float* __restrict__ Kg, const float* __restrict__ Vg,
    short* __restrict__ Kbf, char* __restrict__ Vtg,
    float* __restrict__ kn2g, float* __restrict__ sumg) {
  const int tid = threadIdx.x, bid = blockIdx.x;
  const int st = bid & 31, h = (bid >> 5) & 15, b = bid >> 9;
  const int s0 = st * 64, bh = b * 16 + h;
  if (bid == 0 && tid == 0) *sumg = 0.0f;

  // K + kn2
  const int r64 = tid >> 2, ec = (tid & 3) * 16;
  const float4* kp = (const float4*)(Kg + (((size_t)b * Ss + s0 + r64) * Hh + h) * Ee + ec);
  float4 k0 = kp[0], k1 = kp[1], k2 = kp[2], k3 = kp[3];
  float kn = sq4(k0) + sq4(k1) + sq4(k2) + sq4(k3);
  kn += __shfl_xor(kn, 1);
  kn += __shfl_xor(kn, 2);
  if ((tid & 3) == 0) kn2g[(size_t)bh * Ss + s0 + r64] = kn;
  short* ko = Kbf + ((size_t)bh * Ss + s0 + r64) * Ee + ec;
  *(short8*)(ko)     = pack8(k0, k1);
  *(short8*)(ko + 8) = pack8(k2, k3);

  // V: 4x4 register transpose -> rotated-granule V^T store
  const int sq = tid >> 4;      // s-strip (4 cols) within the 64-block
  const int eq = tid & 15;      // d rows eq*4 .. +3
  const float* vb = Vg + (((size_t)b * Ss + s0 + sq * 4) * Hh + h) * Ee + eq * 4;
  float4 r0 = *(const float4*)(vb);
  float4 r1 = *(const float4*)(vb + Hh * Ee);
  float4 r2 = *(const float4*)(vb + 2 * Hh * Ee);
  float4 r3 = *(const float4*)(vb + 3 * Hh * Ee);
  const int fsrc = ((sq >> 3) << 2) + (sq & 3);  // cp*4 + q4s
  const int half = (sq >> 2) & 1;
#pragma unroll
  for (int j = 0; j < 4; ++j) {
    const int d = eq * 4 + j;
    const int pos = (fsrc + (d & 7)) & 7;
    char* dst = Vtg + ((size_t)bh * 64 + d) * 4096 + st * 128 + pos * 16 + half * 8;
    uint2 t;
    t.x = __builtin_amdgcn_perm(bfrnd((&r1.x)[j]), bfrnd((&r0.x)[j]), 0x07060302u);
    t.y = __builtin_amdgcn_perm(bfrnd((&r3.x)[j]), bfrnd((&r2.x)[j]), 0x07060302u);
    *(uint2*)dst = t;
  }
}

// ---- Main: flash attention, S^T orientation, BK=64, 2 l-groups, P in regs ----
// LDS: K 2x8192 [0,16384)  V^T 2x8192 [16384,32768)  kn2 [32768,40960)
constexpr int KB0 = 0, VB0 = 16384, KN2 = 32768;

__global__ __launch_bounds__(256, 4) void geom_attn_kernel(
    const float* __restrict__ Qg, const char* __restrict__ Kbf,
    const char* __restrict__ Vtg, const float* __restrict__ kn2g,
    float* __restrict__ outg, float* __restrict__ sumg) {
  __shared__ __align__(16) char smem[40960];

  const int tid = threadIdx.x, w = tid >> 6, lane = tid & 63;
  const int c = lane & 15, q4 = lane >> 4;
  const int bid = blockIdx.x;
  const int lt = bid & 15, h = (bid >> 4) & 15, b = bid >> 8;
  const int bh = b * 16 + h;
  const int l0 = lt * 128 + w * 32;

  // Q fragments (B-operand of QK), pre-scaled by S2E; qn2 in S2E^2 units
  short8 qb[2][2];
  float qn2v[2];
#pragma unroll
  for (int g = 0; g < 2; ++g) {
    const float4* qp = (const float4*)(Qg + (((size_t)b * Ll + l0 + g * 16 + c) * Hh + h) * Ee);
    float4 a0 = mul4(qp[2 * q4], S2E),     a1 = mul4(qp[2 * q4 + 1], S2E);
    float4 a2 = mul4(qp[8 + 2 * q4], S2E), a3 = mul4(qp[9 + 2 * q4], S2E);
    float qn = sq4(a0) + sq4(a1) + sq4(a2) + sq4(a3);
    qn += __shfl_xor(qn, 16);
    qn += __shfl_xor(qn, 32);
    qn2v[g] = qn;
    qb[g][0] = pack8(a0, a1);
    qb[g][1] = pack8(a2, a3);
  }

  // staging pointers: flat granule f = tid (instr0), tid+256 (instr1)
  const int rr = tid >> 3, gk = ((tid & 7) ^ (rr & 7));
  const char* kS = Kbf + (size_t)bh * (Ss * 128) + rr * 128 + gk * 16;
  const char* vS = Vtg + (size_t)bh * (64 * 4096) + rr * 4096 + (tid & 7) * 16;
  char* kD = smem + KB0 + w * 1024;  // + pbuf*8192, +4096 for instr1
  char* vD = smem + VB0 + w * 1024;

  // kn2 -> LDS once (8 KB)
  {
    const char* knS = (const char*)kn2g + (size_t)bh * 8192 + w * 1024 + lane * 16;
    GLL(knS, smem + KN2 + w * 1024);
    GLL(knS + 4096, smem + KN2 + w * 1024 + 4096);
  }
  // prologue: tile 0 -> buf 0
  GLL(kS, kD);
  GLL(kS + 4096, kD + 4096);
  GLL(vS, vD);
  GLL(vS + 131072, vD + 4096);
  kS += 8192;
  vS += 128;

  // fragment byte-offsets
  const int kOff = c * 128 + ((q4 ^ (c & 7)) << 4);   // + ct*2048 ; second half ^64
  const int vRow = c * 128;                           // + dt*2048
  floatx4 o[2][4] = {};
  float lp0 = 0.f, lp1 = 0.f, scsum = 0.f;

  for (int it = 0; it < 32; ++it) {
    const int p = it & 1;
    __syncthreads();  // tile it resident in buf p (vmcnt drained by barrier)
    // prefetch tile it+1 into buf p^1 (drains at NEXT barrier)
    GLL(kS, kD + (p ^ 1) * 8192);
    GLL(kS + 4096, kD + (p ^ 1) * 8192 + 4096);
    GLL(vS, vD + (p ^ 1) * 8192);
    GLL(vS + 131072, vD + (p ^ 1) * 8192 + 4096);
    kS += 8192;
    vS += 128;

    const char* Kb = smem + KB0 + p * 8192;
    const char* Vb = smem + VB0 + p * 8192;

    // ---- QK^T scores; lane holds s = ct*16+q4*4+r, l = c; P stays in regs ----
    short4v pb[4][2];
#pragma unroll
    for (int ct = 0; ct < 4; ++ct) {
      short8 ka0 = *(const short8*)(Kb + ct * 2048 + kOff);
      short8 ka1 = *(const short8*)(Kb + ct * 2048 + (kOff ^ 64));
      float4 knv = *(const float4*)(smem + KN2 + it * 256 + ct * 64 + q4 * 16);
#pragma unroll
      for (int g = 0; g < 2; ++g) {
        floatx4 d = {0.f, 0.f, 0.f, 0.f};
        d = MFMA32(ka0, qb[g][0], d);
        d = MFMA32(ka1, qb[g][1], d);
        float pe[4];
#pragma unroll
        for (int r = 0; r < 4; ++r) {
          float dot = d[r];
          float w2 = fmaf(-dot, dot, qn2v[g] * (&knv.x)[r]);
          w2 = fmaxf(w2, EPS2);
          float rt = __builtin_amdgcn_sqrtf(w2);  // score * log2e
          scsum += rt;
          float e = __builtin_amdgcn_exp2f(rt);
          if (g == 0) lp0 += e; else lp1 += e;
          pe[r] = e;
        }
        uint2 pk;  // truncation bf16 pack
        pk.x = __builtin_amdgcn_perm(__builtin_bit_cast(unsigned, pe[1]),
                                     __builtin_bit_cast(unsigned, pe[0]), 0x07060302u);
        pk.y = __builtin_amdgcn_perm(__builtin_bit_cast(unsigned, pe[3]),
                                     __builtin_bit_cast(unsigned, pe[2]), 0x07060302u);
        pb[ct][g] = __builtin_bit_cast(short4v, pk);
      }
    }

    // ---- O^T += V^T . P^T via K=16 MFMA; V A-frags b128 (rotated granules) ----
#pragma unroll
    for (int cp = 0; cp < 2; ++cp) {
      const int gsel = (((cp << 2) + q4 + (c & 7)) & 7) << 4;
#pragma unroll
      for (int dt = 0; dt < 4; ++dt) {
        short8 vv = *(const short8*)(Vb + dt * 2048 + vRow + gsel);
        short4v va0 = __builtin_shufflevector(vv, vv, 0, 1, 2, 3);  // ct=2cp
        short4v va1 = __builtin_shufflevector(vv, vv, 4, 5, 6, 7);  // ct=2cp+1
#pragma unroll
        for (int g = 0; g < 2; ++g) {
          o[g][dt] = MFMA16(va0, pb[2 * cp][g], o[g][dt]);
          o[g][dt] = MFMA16(va1, pb[2 * cp + 1][g], o[g][dt]);
        }
      }
    }
  }

  __builtin_amdgcn_s_waitcnt(0);  // drain trailing prefetch before LDS dealloc
  __syncthreads();

  // l-sums: lane (c,q4) covered s ≡ q4-quads for row l=c -> fold q4 replicas
  lp0 += __shfl_xor(lp0, 16); lp0 += __shfl_xor(lp0, 32);
  lp1 += __shfl_xor(lp1, 16); lp1 += __shfl_xor(lp1, 32);

  // O^T store: lane holds O^T[dt*16+q4*4+r][l=c] -> float4 per dt
#pragma unroll
  for (int g = 0; g < 2; ++g) {
    float inv = 1.0f / (g == 0 ? lp0 : lp1);
    float* orow = outg + (((size_t)b * Ll + l0 + g * 16 + c) * Hh + h) * Ee;
#pragma unroll
    for (int dt = 0; dt < 4; ++dt) {
      float4 st;
      st.x = o[g][dt][0] * inv;
      st.y = o[g][dt][1] * inv;
      st.z = o[g][dt][2] * inv;
      st.w = o[g][dt][3] * inv;
      *(float4*)(orow + dt * 16 + q4 * 4) = st;
    }
  }

  // mean|scores|
  scsum += __shfl_xor(scsum, 1);
  scsum += __shfl_xor(scsum, 2);
  scsum += __shfl_xor(scsum, 4);
  scsum += __shfl_xor(scsum, 8);
  scsum += __shfl_xor(scsum, 16);
  scsum += __shfl_xor(scsum, 32);
  if (lane == 0) atomicAdd(sumg, scsum * SUM_SCALE);
}

extern "C" void kernel_launch(void* const* d_in, const int* in_sizes, int n_in,
                              void* d_out, int out_size, void* d_ws, size_t ws_size,
                              hipStream_t stream) {
  const float* Q = (const float*)d_in[0];
  const float* K = (const float*)d_in[1];
  const float* V = (const float*)d_in[2];
  float* out   = (float*)d_out;
  float* sumsc = out + (size_t)Bb * Ll * Hh * Ee;

  // workspace: Kbf 16.78 MB | Vt 16.78 MB | kn2 0.52 MB (ws >= 34.1 MB)
  short* Kbf = (short*)d_ws;
  char*  Vtg = (char*)(Kbf + (size_t)Bb * Hh * Ss * Ee);
  float* kn2 = (float*)(Vtg + (size_t)Bb * Hh * Ee * Ss * 2);

  hipLaunchKernelGGL(geom_pre_kernel, dim3(Bb * Hh * (Ss / 64)), dim3(256), 0,
                     stream, K, V, Kbf, Vtg, kn2, sumsc);
  hipLaunchKernelGGL(geom_attn_kernel, dim3(Bb * Hh * (Ll / 128)), dim3(256), 0,
                     stream, Q, (const char*)Kbf, (const char*)Vtg, kn2, out, sumsc);
}